// Round 2
// baseline (114.475 us; speedup 1.0000x reference)
//
#include <hip/hip_runtime.h>
#include <stdint.h>

// Problem constants (match reference setup_inputs)
#define BB   16
#define CC   64
#define LL   8192
#define OO   64
#define KK   3
#define TT   64        // positions per block tile
#define XSW  72        // xs LDS row stride (bf16 elems); 144B = 16B-aligned, bank step 36%32=4

typedef __attribute__((ext_vector_type(8))) short short8;     // 8 bf16 = 4 VGPRs (MFMA A/B frag)
typedef __attribute__((ext_vector_type(4))) float float4_t;   // MFMA C/D frag

__device__ __forceinline__ ushort f2bf(float f) {
    uint32_t u = __float_as_uint(f);
    return (ushort)((u + 0x7FFFu + ((u >> 16) & 1u)) >> 16);  // RNE
}
__device__ __forceinline__ float bf2f(ushort h) {
    return __uint_as_float(((uint32_t)h) << 16);
}

// Pre-kernel: weight [O][C][K] fp32 -> wt [O][K*64 + c] bf16 (row-major over ck=k*64+c)
__global__ void wt_prep(const float* __restrict__ w, ushort* __restrict__ wt) {
    int idx = blockIdx.x * 256 + threadIdx.x;
    if (idx < OO * CC * KK) {
        int f = idx / (CC * KK);
        int rem = idx - f * (CC * KK);
        int c = rem / KK;
        int k = rem - c * KK;
        wt[f * (KK * CC) + k * CC + c] = f2bf(w[idx]);
    }
}

__global__ __launch_bounds__(256, 4) void deform_main(
    const float* __restrict__ x, const float* __restrict__ offs,
    const ushort* __restrict__ wt, const float* __restrict__ bias,
    float* __restrict__ out) {

    __shared__ ushort xs[67 * XSW];       // x tile, [pos][c], bf16  (~9.6 KB)
    __shared__ int    Ul[TT * KK];        // local floor index per (n,k)
    __shared__ float  W0s[TT * KK], W1s[TT * KK];

    const int tid  = threadIdx.x;
    const int bb   = blockIdx.x >> 7;     // / (LL/TT = 128)
    const int tile = blockIdx.x & 127;
    const int ts   = tile * TT;

    // ---- Phase 1a: x tile -> LDS (transposed, bf16). padded pos p = ts+i-1, i in [0,67) ----
    {
        const float* xb = x + (size_t)bb * (CC * LL);
        #pragma unroll
        for (int i = 0; i < 17; i++) {
            int idx = tid + i * 256;
            if (idx < 64 * 67) {
                int c = idx / 67;
                int p = idx - c * 67;
                int j = ts + p - 1;                 // unpadded index, reflect at edges
                if (j < 0) j = -j;
                if (j >= LL) j = 2 * LL - 2 - j;
                xs[p * XSW + c] = f2bf(xb[c * LL + j]);
            }
        }
    }

    // ---- Phase 1b: offsets -> (U, w0, w1) per (n,k) ----
    if (tid < TT * KK) {
        int n = tid / 3;
        int k = tid - n * 3;
        float off = offs[((size_t)bb * LL + ts + n) * 3 + k];
        float t0  = (float)(ts + n);
        float T   = t0 + (float)k + off;
        T = fmaxf(T, t0);
        T = fminf(T, t0 + 2.0f);
        int U = (int)floorf(T);
        if (U > LL) U = LL;                 // clip to Lp-2 = 8192
        float Uf = (float)U;
        Ul[tid]  = U - ts;                  // in [n, n+2] -> xs rows valid
        W0s[tid] = fmaxf(0.0f, 1.0f - fabsf(Uf - T));
        W1s[tid] = fmaxf(0.0f, 1.0f - fabsf(Uf + 1.0f - T));
    }
    __syncthreads();

    // ---- Phase 2: fused blend + GEMM. Waves split by n: wave wv owns n in [16wv, 16wv+16).
    // B-frag built in registers: B[n=lr][k0+j] = w0*xs[u][c0+j] + w1*xs[u+1][c0+j].
    // A-frag straight from global wt (12 KB, L2-resident across all 2048 blocks).
    const int lane = tid & 63;
    const int wv   = tid >> 6;
    const int lr   = lane & 15;   // n within tile (B), f within tile (A), col for C
    const int q    = lane >> 4;   // k-quad
    const int n    = wv * 16 + lr;

    float4_t acc0 = {0.f, 0.f, 0.f, 0.f};
    float4_t acc1 = acc0, acc2 = acc0, acc3 = acc0;

    #pragma unroll
    for (int kk = 0; kk < 6; kk++) {
        const int k  = kk >> 1;                  // kernel tap (k0/64)
        const int k0 = kk * 32 + q * 8;          // ck index of this lane's 8 elems
        const int c0 = k0 & 63;                  // channel offset (stays within one tap)
        const int nk = n * KK + k;
        const int u  = Ul[nk];
        const float w0 = W0s[nk], w1 = W1s[nk];
        union { uint4 v; ushort u16[8]; } r0, r1;
        r0.v = *(const uint4*)&xs[u * XSW + c0];
        r1.v = *(const uint4*)&xs[(u + 1) * XSW + c0];
        union { short8 s; uint32_t u32[4]; } bf;
        #pragma unroll
        for (int j = 0; j < 4; j++) {
            float v0 = w0 * bf2f(r0.u16[2 * j])     + w1 * bf2f(r1.u16[2 * j]);
            float v1 = w0 * bf2f(r0.u16[2 * j + 1]) + w1 * bf2f(r1.u16[2 * j + 1]);
            bf.u32[j] = (uint32_t)f2bf(v0) | ((uint32_t)f2bf(v1) << 16);
        }
        short8 a0 = *(const short8*)&wt[(0 * 16 + lr) * (KK * CC) + k0];
        short8 a1 = *(const short8*)&wt[(1 * 16 + lr) * (KK * CC) + k0];
        short8 a2 = *(const short8*)&wt[(2 * 16 + lr) * (KK * CC) + k0];
        short8 a3 = *(const short8*)&wt[(3 * 16 + lr) * (KK * CC) + k0];
        acc0 = __builtin_amdgcn_mfma_f32_16x16x32_bf16(a0, bf.s, acc0, 0, 0, 0);
        acc1 = __builtin_amdgcn_mfma_f32_16x16x32_bf16(a1, bf.s, acc1, 0, 0, 0);
        acc2 = __builtin_amdgcn_mfma_f32_16x16x32_bf16(a2, bf.s, acc2, 0, 0, 0);
        acc3 = __builtin_amdgcn_mfma_f32_16x16x32_bf16(a3, bf.s, acc3, 0, 0, 0);
    }

    // ---- Phase 3: epilogue. C/D: col = lane&15 (n within tile), row = q*4 + r (f within m-tile)
    const int col = ts + wv * 16 + lr;
    float4_t accs[4] = {acc0, acc1, acc2, acc3};
    #pragma unroll
    for (int mt = 0; mt < 4; mt++) {
        const int f0 = mt * 16 + q * 4;
        float4_t bv = *(const float4_t*)&bias[f0];
        float* ob = out + ((size_t)bb * OO + f0) * LL + col;
        #pragma unroll
        for (int r = 0; r < 4; r++) {
            ob[(size_t)r * LL] = accs[mt][r] + bv[r];
        }
    }
}

extern "C" void kernel_launch(void* const* d_in, const int* in_sizes, int n_in,
                              void* d_out, int out_size, void* d_ws, size_t ws_size,
                              hipStream_t stream) {
    const float* x    = (const float*)d_in[0];
    const float* offs = (const float*)d_in[1];
    const float* w    = (const float*)d_in[2];
    const float* bias = (const float*)d_in[3];
    float* out = (float*)d_out;
    ushort* wt = (ushort*)d_ws;   // 12288 bf16 = 24576 B scratch

    hipLaunchKernelGGL(wt_prep, dim3((OO * CC * KK + 255) / 256), dim3(256), 0, stream, w, wt);
    hipLaunchKernelGGL(deform_main, dim3(BB * (LL / TT)), dim3(256), 0, stream,
                       x, offs, wt, bias, out);
}

// Round 3
// 113.381 us; speedup vs baseline: 1.0097x; 1.0097x over previous
//
#include <hip/hip_runtime.h>
#include <hip/hip_bf16.h>
#include <stdint.h>

// Problem constants (match reference setup_inputs)
#define BB   16
#define CC   64
#define LL   8192
#define OO   64
#define KK   3
#define TT   64        // positions per block tile
#define XSW  68        // xs fp32 row stride: 272B rows, 16B-aligned, bank step 4

typedef __attribute__((ext_vector_type(8))) short short8;     // 8 bf16 = 4 VGPRs (MFMA A/B frag)
typedef __attribute__((ext_vector_type(4))) float float4_t;   // MFMA C/D frag

__device__ __forceinline__ ushort f2bf(float f) {
    uint32_t u = __float_as_uint(f);
    return (ushort)((u + 0x7FFFu + ((u >> 16) & 1u)) >> 16);  // RNE
}

__device__ __forceinline__ uint32_t pk2(float lo, float hi) {
    float2 t; t.x = lo; t.y = hi;
    __hip_bfloat162 h = __float22bfloat162_rn(t);
    return *(uint32_t*)&h;
}

// Pre-kernel: weight [O][C][K] fp32 -> wt [O][K*64 + c] bf16 (row-major over ck=k*64+c)
__global__ void wt_prep(const float* __restrict__ w, ushort* __restrict__ wt) {
    int idx = blockIdx.x * 256 + threadIdx.x;
    if (idx < OO * CC * KK) {
        int f = idx / (CC * KK);
        int rem = idx - f * (CC * KK);
        int c = rem / KK;
        int k = rem - c * KK;
        wt[f * (KK * CC) + k * CC + c] = f2bf(w[idx]);
    }
}

__global__ __launch_bounds__(256, 4) void deform_main(
    const float* __restrict__ x, const float* __restrict__ offs,
    const ushort* __restrict__ wt, const float* __restrict__ bias,
    float* __restrict__ out) {

    // xs[pp][c] fp32, pp=0..71 <-> x_pad[ts-3+pp]; raw store xs[pp]=x[ts-4+pp].
    // GEMM reads pp in [3, 69] only. 19584 B.
    __shared__ float xs[72 * XSW];

    const int tid  = threadIdx.x;
    const int bb   = blockIdx.x >> 7;     // / (LL/TT = 128)
    const int tile = blockIdx.x & 127;
    const int ts   = tile * TT;
    const int lane = tid & 63;
    const int wv   = tid >> 6;

    // ---- Phase 1: x tile -> LDS, fp32, transposed, aligned float4 loads ----
    {
        const float* xb = x + (size_t)bb * (CC * LL);
        const int c     = wv * 16 + (lane >> 2);      // channel this lane stages
        const int fb    = lane & 3;                   // float4-index base within row
        const float* xrow = xb + (size_t)c * LL;
        #pragma unroll
        for (int i = 0; i < 5; i++) {
            int fi = fb + 4 * i;                      // 0..19, need 0..17
            int j0 = ts - 4 + 4 * fi;
            if (fi < 18 && j0 >= 0 && j0 <= LL - 4) { // skip OOB (edge tiles fix below)
                float4 v = *(const float4*)(xrow + j0);
                float* dst = &xs[(4 * fi) * XSW + c];
                dst[0 * XSW] = v.x; dst[1 * XSW] = v.y;
                dst[2 * XSW] = v.z; dst[3 * XSW] = v.w;
            }
        }
        // reflect fix-ups (only rows actually read): x_pad[0]=x[1], x_pad[8193]=x[8190]
        if (tile == 0   && tid < 64) xs[3 * XSW + tid]  = xb[(size_t)tid * LL + 1];
        if (tile == 127 && tid < 64) xs[68 * XSW + tid] = xb[(size_t)tid * LL + (LL - 2)];
    }

    // ---- Phase 1b: per-lane (U, w0, w1) for this lane's n, all 3 taps, in registers ----
    const int lr = lane & 15;     // n within tile (B), f within m-tile (A), col for C
    const int q  = lane >> 4;     // k-quad
    const int n  = wv * 16 + lr;
    int   ppk[KK];
    float w0k[KK], w1k[KK];
    {
        const float* ob = offs + ((size_t)bb * LL + ts + n) * KK;
        const float t0 = (float)(ts + n);
        #pragma unroll
        for (int k = 0; k < KK; k++) {
            float T = t0 + (float)k + ob[k];
            T = fmaxf(T, t0);
            T = fminf(T, t0 + 2.0f);
            int U = (int)floorf(T);
            if (U > LL) U = LL;                       // clip to Lp-2 = 8192
            float Uf = (float)U;
            ppk[k] = U - ts + 3;                      // xs row of lower neighbor
            w0k[k] = fmaxf(0.0f, 1.0f - fabsf(Uf - T));
            w1k[k] = fmaxf(0.0f, 1.0f - fabsf(Uf + 1.0f - T));
        }
    }
    __syncthreads();

    // ---- Phase 2: fused blend + GEMM. Wave wv owns n-tile [16wv, 16wv+16). ----
    float4_t acc0 = {0.f, 0.f, 0.f, 0.f};
    float4_t acc1 = acc0, acc2 = acc0, acc3 = acc0;

    #pragma unroll
    for (int kk = 0; kk < 6; kk++) {
        const int k0 = kk * 32 + q * 8;               // ck index of this lane's 8 elems
        const int k  = k0 >> 6;                       // kernel tap
        const int c0 = k0 & 63;                       // channel offset (single tap)
        const int pp = ppk[k];
        const float w0 = w0k[k], w1 = w1k[k];
        const float4 r0a = *(const float4*)&xs[pp * XSW + c0];
        const float4 r0b = *(const float4*)&xs[pp * XSW + c0 + 4];
        const float4 r1a = *(const float4*)&xs[(pp + 1) * XSW + c0];
        const float4 r1b = *(const float4*)&xs[(pp + 1) * XSW + c0 + 4];
        union { short8 s; uint32_t u32[4]; } bf;
        bf.u32[0] = pk2(w0 * r0a.x + w1 * r1a.x, w0 * r0a.y + w1 * r1a.y);
        bf.u32[1] = pk2(w0 * r0a.z + w1 * r1a.z, w0 * r0a.w + w1 * r1a.w);
        bf.u32[2] = pk2(w0 * r0b.x + w1 * r1b.x, w0 * r0b.y + w1 * r1b.y);
        bf.u32[3] = pk2(w0 * r0b.z + w1 * r1b.z, w0 * r0b.w + w1 * r1b.w);
        short8 a0 = *(const short8*)&wt[(0 * 16 + lr) * (KK * CC) + k0];
        short8 a1 = *(const short8*)&wt[(1 * 16 + lr) * (KK * CC) + k0];
        short8 a2 = *(const short8*)&wt[(2 * 16 + lr) * (KK * CC) + k0];
        short8 a3 = *(const short8*)&wt[(3 * 16 + lr) * (KK * CC) + k0];
        acc0 = __builtin_amdgcn_mfma_f32_16x16x32_bf16(a0, bf.s, acc0, 0, 0, 0);
        acc1 = __builtin_amdgcn_mfma_f32_16x16x32_bf16(a1, bf.s, acc1, 0, 0, 0);
        acc2 = __builtin_amdgcn_mfma_f32_16x16x32_bf16(a2, bf.s, acc2, 0, 0, 0);
        acc3 = __builtin_amdgcn_mfma_f32_16x16x32_bf16(a3, bf.s, acc3, 0, 0, 0);
    }

    // ---- Phase 3: epilogue. C/D: col = lane&15 (n within tile), row = q*4 + r (f) ----
    const int col = ts + wv * 16 + lr;
    float4_t accs[4] = {acc0, acc1, acc2, acc3};
    #pragma unroll
    for (int mt = 0; mt < 4; mt++) {
        const int f0 = mt * 16 + q * 4;
        float4_t bv = *(const float4_t*)&bias[f0];
        float* ob = out + ((size_t)bb * OO + f0) * LL + col;
        #pragma unroll
        for (int r = 0; r < 4; r++) {
            ob[(size_t)r * LL] = accs[mt][r] + bv[r];
        }
    }
}

extern "C" void kernel_launch(void* const* d_in, const int* in_sizes, int n_in,
                              void* d_out, int out_size, void* d_ws, size_t ws_size,
                              hipStream_t stream) {
    const float* x    = (const float*)d_in[0];
    const float* offs = (const float*)d_in[1];
    const float* w    = (const float*)d_in[2];
    const float* bias = (const float*)d_in[3];
    float* out = (float*)d_out;
    ushort* wt = (ushort*)d_ws;   // 12288 bf16 = 24576 B scratch

    hipLaunchKernelGGL(wt_prep, dim3((OO * CC * KK + 255) / 256), dim3(256), 0, stream, w, wt);
    hipLaunchKernelGGL(deform_main, dim3(BB * (LL / TT)), dim3(256), 0, stream,
                       x, offs, wt, bias, out);
}